// Round 1
// baseline (193.639 us; speedup 1.0000x reference)
//
#include <hip/hip_runtime.h>

#define N_SAMP   4410000
#define WSZ      441
#define NC       10000
#define NB       100
#define LB       100          // chunks per block (NB*LB == NC)
#define PF       10           // prefetch ring depth (LB % PF == 0)
#define TWO_PI_F 6.28318530717958647692f
#define FADE_START (N_SAMP - 256)

// workspace layout (floats)
#define WS_WT   0
#define WS_SC   448                    // [0]=decay [1]=feedbackamt [2]=gain
#define WS_V    512
#define WS_VHR  (WS_V   + NB*448)
#define WS_VHI  (WS_VHR + NB*448)
#define WS_SHR  (WS_VHI + NB*448)
#define WS_SHI  (WS_SHR + NB*448)
#define WS_SB   (WS_SHI + NB*448)
#define WS_NEED ((size_t)(WS_SB + NB*448) * sizeof(float))

static_assert(NB * LB == NC, "block decomposition");
static_assert(LB % PF == 0, "ring divides block");

__device__ __forceinline__ void bq_coefs(float f, float q,
    float& c0, float& c1, float& c2, float& c3, float& c4)
{
    float w0 = TWO_PI_F * f / 44100.0f;
    float cw = cosf(w0), sw = sinf(w0);
    float al = sw / (2.0f * q);
    float a0 = 1.0f + al;
    c0 = ((1.0f - cw) * 0.5f) / a0;
    c1 = (1.0f - cw) / a0;
    c2 = ((1.0f - cw) * 0.5f) / a0;
    c3 = (-2.0f * cw) / a0;
    c4 = (1.0f - al) / a0;
}

// chained pair of biquads (direct form II transposed), causal per-sample
__device__ __forceinline__ void run_biquads(const float* __restrict__ noise,
    float lpf, float lpq, float f2, float* dst)
{
    float c10,c11,c12,c13,c14, c20,c21,c22,c23,c24;
    bq_coefs(lpf, lpq, c10,c11,c12,c13,c14);
    bq_coefs(f2, 0.707f, c20,c21,c22,c23,c24);
    float s11=0.f,s12=0.f,s21=0.f,s22=0.f;
    for (int m = 0; m < WSZ; ++m) {
        float x  = noise[m];
        float y1 = c10*x + s11;
        s11 = c11*x - c13*y1 + s12;
        s12 = c12*x - c14*y1;
        float y2 = c20*y1 + s21;
        s21 = c21*y1 - c23*y2 + s22;
        s22 = c22*y1 - c24*y2;
        dst[m] = y2;
    }
}

// ---------------- kernel A: MLP latents + wavetable ----------------
__global__ __launch_bounds__(128) void k_setup(
    const float* __restrict__ h, const float* __restrict__ noise,
    const float* __restrict__ W1, const float* __restrict__ b1v,
    const float* __restrict__ W2, const float* __restrict__ b2v,
    const float* __restrict__ lpcut, float* __restrict__ ws)
{
    __shared__ float hid[128];
    __shared__ float lat[5];
    const int tid = threadIdx.x;
    float acc = b1v[tid];
    #pragma unroll
    for (int i = 0; i < 9; ++i) acc = acc + h[i] * W1[i*128 + tid];
    hid[tid] = fmaxf(acc, 0.0f);
    __syncthreads();
    if (tid < 5) {
        float a = b2v[tid];
        for (int k = 0; k < 128; ++k) a = a + hid[k] * W2[k*5 + tid];
        lat[tid] = fmaxf(a, 0.0f);
    }
    __syncthreads();
    if (tid == 0) {
        const float decay = fminf(fmaxf(lat[0]/10.0f + 0.9f, 0.9f), 0.999f);
        const float lpf   = fminf(fmaxf(lat[1]*44100.0f/4.0f, 100.0f), 22049.0f);
        const float lpq   = fminf(fmaxf(lat[2], 0.1f), 0.999f);
        ws[WS_SC+0] = decay;
        ws[WS_SC+1] = lat[3];
        ws[WS_SC+2] = lat[4];
        run_biquads(noise, lpf, lpq, lpcut[0], ws + WS_WT);
    }
}

// ---------------- kernel B: per-block local scan (zero init; block 0 from wt) ----------------
__global__ __launch_bounds__(448) void k_local(
    const float* __restrict__ fb, float* __restrict__ out, float* __restrict__ ws)
{
    __shared__ float buf[2][448];
    const int b = blockIdx.x;
    const int j = threadIdx.x;
    const bool act = j < WSZ;
    const float decay = ws[WS_SC+0];
    const float famt  = ws[WS_SC+1];
    const float d2 = 0.5f * decay;
    const int jm1 = (j == 0) ? (WSZ-1) : (j-1);
    const int i0 = b * LB;
    float cur = 0.0f;
    if (b == 0 && act) cur = ws[WS_WT + j];
    float r[PF];
    #pragma unroll
    for (int p = 0; p < PF; ++p)
        r[p] = act ? fb[(i0 + p) * WSZ + j] : 0.0f;
    for (int io = 0; io < LB/PF; ++io) {
        #pragma unroll
        for (int p = 0; p < PF; ++p) {
            const int i = io*PF + p;
            float x = cur + famt * r[p];
            int inext = i0 + i + PF;                 // prefetch; clamp within own block
            if (inext > i0 + LB - 1) inext = i0 + LB - 1;
            r[p] = act ? fb[inext * WSZ + j] : 0.0f;
            buf[i&1][j] = x;
            __syncthreads();
            float prev = buf[i&1][jm1];
            cur = d2 * (x + prev);
            if (act) out[(i0 + i) * WSZ + j] = cur;
        }
    }
    if (act) ws[WS_V + b*448 + j] = cur;            // block end state v_b
}

// ---------------- kernel C1: DFT of v_b (b = 0..NB-2) ----------------
__global__ __launch_bounds__(448) void k_dft(float* __restrict__ ws)
{
    const int b = blockIdx.x;
    const int j = threadIdx.x;
    if (j >= WSZ) return;
    const float* v = ws + WS_V + b*448;
    const float cb = -TWO_PI_F / 441.0f;
    float steps, stepc;
    sincosf(cb * (float)j, &steps, &stepc);          // e^{-2*pi*i*j/441}
    float wr = 1.0f, wi = 0.0f, ar = 0.0f, ai = 0.0f;
    int pm = 0;                                      // (j*m) mod 441
    for (int m = 0; m < WSZ; ++m) {
        if ((m & 31) == 0) sincosf(cb * (float)pm, &wi, &wr);   // resync (drift cap)
        float vm = v[m];                             // wave-uniform -> s_load
        ar = fmaf(vm, wr, ar);
        ai = fmaf(vm, wi, ai);
        pm += j; if (pm >= WSZ) pm -= WSZ;
        float nr = wr*stepc - wi*steps;
        float ni = wr*steps + wi*stepc;
        wr = nr; wi = ni;
    }
    ws[WS_VHR + b*448 + j] = ar;
    ws[WS_VHI + b*448 + j] = ai;
}

// ---------------- kernel C2: per-mode boundary scan  S_{b+1} = lambda^L S_b + V_b ----------------
__global__ __launch_bounds__(448) void k_scan(float* __restrict__ ws)
{
    const int j = threadIdx.x;
    if (j >= WSZ) return;
    const float decay = ws[WS_SC+0];
    float s, c;
    sincosf(TWO_PI_F * (float)j / 441.0f, &s, &c);
    float lr = 0.5f*decay*(1.0f + c);                // lambda_j = d/2 (1 + e^{-2 pi i j/441})
    float li = -0.5f*decay*s;
    float pr = 1.0f, pi = 0.0f, br = lr, bi = li;    // lambda^LB by binary powering
    int e = LB;
    while (e) {
        if (e & 1) { float t = pr*br - pi*bi; pi = pr*bi + pi*br; pr = t; }
        float t2 = br*br - bi*bi; bi = 2.0f*br*bi; br = t2;
        e >>= 1;
    }
    float sr = ws[WS_VHR + j];                       // S_1 = Vhat_0
    float si = ws[WS_VHI + j];
    for (int b = 1; b < NB; ++b) {
        ws[WS_SHR + b*448 + j] = sr;
        ws[WS_SHI + b*448 + j] = si;
        if (b < NB-1) {
            float vr = ws[WS_VHR + b*448 + j];
            float vi = ws[WS_VHI + b*448 + j];
            float nr = pr*sr - pi*si + vr;
            si = pr*si + pi*sr + vi;
            sr = nr;
        }
    }
}

// ---------------- kernel C3: IDFT of S_b (b = 1..NB-1) ----------------
__global__ __launch_bounds__(448) void k_idft(float* __restrict__ ws)
{
    const int b = blockIdx.x + 1;
    const int m = threadIdx.x;
    if (m >= WSZ) return;
    const float* Sr = ws + WS_SHR + b*448;
    const float* Si = ws + WS_SHI + b*448;
    const float cb = TWO_PI_F / 441.0f;
    float steps, stepc;
    sincosf(cb * (float)m, &steps, &stepc);          // e^{+2*pi*i*m/441}
    float wr = 1.0f, wi = 0.0f, acc = 0.0f;
    int pm = 0;
    for (int jj = 0; jj < WSZ; ++jj) {
        if ((jj & 31) == 0) sincosf(cb * (float)pm, &wi, &wr);
        acc = fmaf(Sr[jj], wr, acc);                 // uniform -> s_load
        acc = fmaf(-Si[jj], wi, acc);
        pm += m; if (pm >= WSZ) pm -= WSZ;
        float nr = wr*stepc - wi*steps;
        float ni = wr*steps + wi*stepc;
        wr = nr; wi = ni;
    }
    ws[WS_SB + b*448 + m] = acc * (1.0f/441.0f);
}

// ---------------- kernel D: correction + fade/env/gain finalize ----------------
__global__ __launch_bounds__(448) void k_final(
    const float* __restrict__ t_in, const float* __restrict__ envp,
    const float* __restrict__ fade, float* __restrict__ out,
    const float* __restrict__ ws)
{
    __shared__ float buf[2][448];
    const int b = blockIdx.x;
    const int j = threadIdx.x;
    const bool act = j < WSZ;
    const float decay = ws[WS_SC+0];
    const float gain  = ws[WS_SC+2];
    const float d2 = 0.5f * decay;
    const float a_  = fabsf(envp[0]) + 1e-3f;
    const float sus = envp[1];
    const float rr  = fabsf(envp[2]) + 1e-3f;
    const float inv_a = 1.0f / a_, inv_r = 1.0f / rr;
    const float T = t_in[N_SAMP - 1];
    const int jm1 = (j == 0) ? (WSZ-1) : (j-1);
    const int i0 = b * LB;
    const bool hasc = (b > 0);
    float corr = 0.0f;
    if (hasc && act) corr = ws[WS_SB + b*448 + j];
    float rz[PF], rt[PF];
    #pragma unroll
    for (int p = 0; p < PF; ++p) {
        int idx = (i0 + p) * WSZ + j;
        rz[p] = act ? out[idx] : 0.0f;
        rt[p] = act ? t_in[idx] : 0.0f;
    }
    for (int io = 0; io < LB/PF; ++io) {
        #pragma unroll
        for (int p = 0; p < PF; ++p) {
            const int i = io*PF + p;
            float z = rz[p], tt = rt[p];
            int inext = i0 + i + PF;                 // prefetch; clamp within own block
            if (inext > i0 + LB - 1) inext = i0 + LB - 1;
            int nidx = inext * WSZ + j;
            rz[p] = act ? out[nidx] : 0.0f;
            rt[p] = act ? t_in[nidx] : 0.0f;
            if (hasc) {                              // corr_k = M corr_{k-1}
                buf[i&1][j] = corr;
                __syncthreads();
                corr = d2 * (corr + buf[i&1][jm1]);
            }
            float val = z + corr;
            const int idx = (i0 + i) * WSZ + j;
            if (idx >= FADE_START) val *= fade[idx - FADE_START];
            float ca  = fminf(fmaxf(tt * inv_a, 0.0f), 1.0f);
            float cr2 = fminf(fmaxf((T - tt) * inv_r, 0.0f), 1.0f);
            float env = ca * cr2 * sus;
            val = val * env * gain;
            if (act) out[idx] = val;
        }
    }
}

// ---------------- fallback: fully sequential single block (no workspace) ----------------
__global__ __launch_bounds__(448) void k_naive(
    const float* __restrict__ fb, const float* __restrict__ h,
    const float* __restrict__ t_in, const float* __restrict__ noise,
    const float* __restrict__ W1, const float* __restrict__ b1v,
    const float* __restrict__ W2, const float* __restrict__ b2v,
    const float* __restrict__ lpcut, const float* __restrict__ envp,
    const float* __restrict__ fade, float* __restrict__ out)
{
    __shared__ float hid[128];
    __shared__ float lat[5];
    __shared__ float wt[WSZ];
    __shared__ float buf[2][448];
    const int j = threadIdx.x;
    if (j < 128) {
        float acc = b1v[j];
        #pragma unroll
        for (int i = 0; i < 9; ++i) acc = acc + h[i] * W1[i*128 + j];
        hid[j] = fmaxf(acc, 0.0f);
    }
    __syncthreads();
    if (j < 5) {
        float a = b2v[j];
        for (int k = 0; k < 128; ++k) a = a + hid[k] * W2[k*5 + j];
        lat[j] = fmaxf(a, 0.0f);
    }
    __syncthreads();
    if (j == 0) {
        float lpf = fminf(fmaxf(lat[1]*44100.0f/4.0f, 100.0f), 22049.0f);
        float lpq = fminf(fmaxf(lat[2], 0.1f), 0.999f);
        run_biquads(noise, lpf, lpq, lpcut[0], wt);
    }
    __syncthreads();
    const float decay = fminf(fmaxf(lat[0]/10.0f + 0.9f, 0.9f), 0.999f);
    const float famt = lat[3];
    const float gain = lat[4];
    const float d2 = 0.5f * decay;
    const float a_  = fabsf(envp[0]) + 1e-3f;
    const float sus = envp[1];
    const float rr  = fabsf(envp[2]) + 1e-3f;
    const float inv_a = 1.0f / a_, inv_r = 1.0f / rr;
    const float T = t_in[N_SAMP - 1];
    const bool act = j < WSZ;
    const int jm1 = (j == 0) ? (WSZ - 1) : (j - 1);
    float cur = act ? wt[j] : 0.0f;
    float rfb[PF], rt[PF];
    #pragma unroll
    for (int p = 0; p < PF; ++p) {
        int idx = p * WSZ + j;
        rfb[p] = act ? fb[idx] : 0.0f;
        rt[p]  = act ? t_in[idx] : 0.0f;
    }
    for (int io = 0; io < NC/PF; ++io) {
        #pragma unroll
        for (int p = 0; p < PF; ++p) {
            const int i = io*PF + p;
            float x = cur + famt * rfb[p];
            float tt = rt[p];
            int inext = i + PF; if (inext > NC-1) inext = NC-1;
            rfb[p] = act ? fb[inext*WSZ + j] : 0.0f;
            rt[p]  = act ? t_in[inext*WSZ + j] : 0.0f;
            buf[i&1][j] = x;
            __syncthreads();
            cur = d2 * (x + buf[i&1][jm1]);
            float val = cur;
            const int idx = i*WSZ + j;
            if (idx >= FADE_START) val *= fade[idx - FADE_START];
            float ca  = fminf(fmaxf(tt * inv_a, 0.0f), 1.0f);
            float cr2 = fminf(fmaxf((T - tt) * inv_r, 0.0f), 1.0f);
            val = val * (ca * cr2 * sus) * gain;
            if (act) out[idx] = val;
        }
    }
}

extern "C" void kernel_launch(void* const* d_in, const int* in_sizes, int n_in,
                              void* d_out, int out_size, void* d_ws, size_t ws_size,
                              hipStream_t stream) {
    const float* fb   = (const float*)d_in[0];
    const float* h    = (const float*)d_in[1];
    const float* t    = (const float*)d_in[2];
    const float* nz   = (const float*)d_in[3];
    const float* W1   = (const float*)d_in[4];
    const float* b1v  = (const float*)d_in[5];
    const float* W2   = (const float*)d_in[6];
    const float* b2v  = (const float*)d_in[7];
    const float* lpc  = (const float*)d_in[8];
    const float* envp = (const float*)d_in[9];
    const float* fade = (const float*)d_in[10];
    float* out = (float*)d_out;
    float* ws  = (float*)d_ws;

    if (ws_size < WS_NEED) {
        k_naive<<<1, 448, 0, stream>>>(fb, h, t, nz, W1, b1v, W2, b2v, lpc, envp, fade, out);
        return;
    }
    k_setup<<<1,    128, 0, stream>>>(h, nz, W1, b1v, W2, b2v, lpc, ws);
    k_local<<<NB,   448, 0, stream>>>(fb, out, ws);
    k_dft  <<<NB-1, 448, 0, stream>>>(ws);
    k_scan <<<1,    448, 0, stream>>>(ws);
    k_idft <<<NB-1, 448, 0, stream>>>(ws);
    k_final<<<NB,   448, 0, stream>>>(t, envp, fade, out, ws);
}

// Round 3
// 154.442 us; speedup vs baseline: 1.2538x; 1.2538x over previous
//
#include <hip/hip_runtime.h>

#define N_SAMP   4410000
#define WSZ      441
#define NC       10000
#define NB       250
#define LB       40           // NB*LB == NC
#define PF       5            // fb prefetch ring depth (LB % PF == 0)
#define TWO_PI_F 6.28318530717958647692f
#define FADE_START (N_SAMP - 256)
#define INV_SR   (1.0f/44100.0f)

// workspace layout (floats)
#define WS_WT   0                          // 441 (padded 448)
#define WS_SC   448                        // [0]=decay [1]=feedbackamt [2]=gain
#define WS_V    512                        // NB*448: v_b end states; later aliased by SB[b] at (b-1)*448
#define WS_VHR  (WS_V + NB*448)            // (NB-1)*224: Re V^ ; scan overwrites in-place with Re S_{b+1}
#define WS_VHI  (WS_VHR + (NB-1)*224)      // (NB-1)*224: Im
#define WS_NEED ((size_t)(WS_VHI + (NB-1)*224) * sizeof(float))

static_assert(NB * LB == NC, "block decomposition");
static_assert(LB % PF == 0, "ring divides block");

__device__ __forceinline__ void bq_coefs(float f, float q,
    float& c0, float& c1, float& c2, float& c3, float& c4)
{
    float w0 = TWO_PI_F * f / 44100.0f;
    float cw = cosf(w0), sw = sinf(w0);
    float al = sw / (2.0f * q);
    float a0 = 1.0f + al;
    c0 = ((1.0f - cw) * 0.5f) / a0;
    c1 = (1.0f - cw) / a0;
    c2 = ((1.0f - cw) * 0.5f) / a0;
    c3 = (-2.0f * cw) / a0;
    c4 = (1.0f - al) / a0;
}

// chained pair of biquads (direct form II transposed), causal per-sample
__device__ __forceinline__ void run_biquads(const float* __restrict__ noise,
    float lpf, float lpq, float f2, float* dst)
{
    float c10,c11,c12,c13,c14, c20,c21,c22,c23,c24;
    bq_coefs(lpf, lpq, c10,c11,c12,c13,c14);
    bq_coefs(f2, 0.707f, c20,c21,c22,c23,c24);
    float s11=0.f,s12=0.f,s21=0.f,s22=0.f;
    for (int m = 0; m < WSZ; ++m) {
        float x  = noise[m];
        float y1 = c10*x + s11;
        s11 = c11*x - c13*y1 + s12;
        s12 = c12*x - c14*y1;
        float y2 = c20*y1 + s21;
        s21 = c21*y1 - c23*y2 + s22;
        s22 = c22*y1 - c24*y2;
        dst[m] = y2;
    }
}

// ---------------- kernel A: MLP latents + wavetable ----------------
__global__ __launch_bounds__(128) void k_setup(
    const float* __restrict__ h, const float* __restrict__ noise,
    const float* __restrict__ W1, const float* __restrict__ b1v,
    const float* __restrict__ W2, const float* __restrict__ b2v,
    const float* __restrict__ lpcut, float* __restrict__ ws)
{
    __shared__ float hid[128];
    __shared__ float lat[5];
    const int tid = threadIdx.x;
    float acc = b1v[tid];
    #pragma unroll
    for (int i = 0; i < 9; ++i) acc = acc + h[i] * W1[i*128 + tid];
    hid[tid] = fmaxf(acc, 0.0f);
    __syncthreads();
    if (tid < 5) {
        float a = b2v[tid];
        for (int k = 0; k < 128; ++k) a = a + hid[k] * W2[k*5 + tid];
        lat[tid] = fmaxf(a, 0.0f);
    }
    __syncthreads();
    if (tid == 0) {
        const float decay = fminf(fmaxf(lat[0]/10.0f + 0.9f, 0.9f), 0.999f);
        const float lpf   = fminf(fmaxf(lat[1]*44100.0f/4.0f, 100.0f), 22049.0f);
        const float lpq   = fminf(fmaxf(lat[2], 0.1f), 0.999f);
        ws[WS_SC+0] = decay;
        ws[WS_SC+1] = lat[3];
        ws[WS_SC+2] = lat[4];
        run_biquads(noise, lpf, lpq, lpcut[0], ws + WS_WT);
    }
}

// ---------------- kernel B: per-block local scan, wave-register state, no barriers ----
// lane j (j<63) holds positions p = 63k + j, k=0..6. Only end state v_b is stored.
// Shift-by-1: sh[k] = shfl(x[k], j-1); lane 0 takes sh[(k+6)%7] (lane62's reg k-1 = pos p-1).
__global__ __launch_bounds__(64) void k_state(
    const float* __restrict__ fb, float* __restrict__ ws)
{
    const int b = blockIdx.x;              // 0..NB-2
    const int j = threadIdx.x;
    const bool act = j < 63;
    const float decay = ws[WS_SC+0];
    const float famt  = ws[WS_SC+1];
    const float d2 = 0.5f * decay;
    const int src = (j == 0) ? 62 : j - 1;
    const int i0 = b * LB;
    float cur[7];
    #pragma unroll
    for (int k = 0; k < 7; ++k)
        cur[k] = (b == 0 && act) ? ws[WS_WT + 63*k + j] : 0.0f;
    float r[PF][7];
    #pragma unroll
    for (int p = 0; p < PF; ++p) {
        #pragma unroll
        for (int k = 0; k < 7; ++k)
            r[p][k] = act ? fb[(i0 + p)*WSZ + 63*k + j] : 0.0f;
    }
    for (int io = 0; io < LB/PF; ++io) {
        #pragma unroll
        for (int p = 0; p < PF; ++p) {
            const int i = i0 + io*PF + p;
            float x[7];
            #pragma unroll
            for (int k = 0; k < 7; ++k) x[k] = fmaf(famt, r[p][k], cur[k]);
            int inext = i + PF; if (inext > i0 + LB - 1) inext = i0 + LB - 1;
            #pragma unroll
            for (int k = 0; k < 7; ++k)
                r[p][k] = act ? fb[inext*WSZ + 63*k + j] : 0.0f;
            float sh[7];
            #pragma unroll
            for (int k = 0; k < 7; ++k) sh[k] = __shfl(x[k], src);
            #pragma unroll
            for (int k = 0; k < 7; ++k) {
                float prev = (j == 0) ? sh[(k+6)%7] : sh[k];
                cur[k] = d2 * (x[k] + prev);
            }
        }
    }
    if (act) {
        #pragma unroll
        for (int k = 0; k < 7; ++k)
            ws[WS_V + b*448 + 63*k + j] = cur[k];
    }
}

// ---------------- kernel C1: forward DFT of v_b, modes 0..220 (conj symmetry) ------
__global__ __launch_bounds__(256) void k_dft(float* __restrict__ ws)
{
    __shared__ float vs_[441];
    const int b = blockIdx.x;              // 0..NB-2
    const int tid = threadIdx.x;
    for (int m = tid; m < 441; m += 256) vs_[m] = ws[WS_V + b*448 + m];
    __syncthreads();
    const int j = tid;
    if (j >= 221) return;
    const float cb = -TWO_PI_F / 441.0f;
    float ss, sc;
    sincosf(cb * (float)j, &ss, &sc);      // step e^{-2 pi i j/441}
    float wr = 1.0f, wi = 0.0f, ar = 0.0f, ai = 0.0f;
    int pm = 0;                            // (j*m) mod 441
    for (int m = 0; m < 441; ++m) {
        if ((m & 31) == 0) sincosf(cb * (float)pm, &wi, &wr);   // resync
        float v = vs_[m];
        ar = fmaf(v, wr, ar);
        ai = fmaf(v, wi, ai);
        pm += j; if (pm >= 441) pm -= 441;
        float nr = wr*sc - wi*ss;
        float ni = wr*ss + wi*sc;
        wr = nr; wi = ni;
    }
    ws[WS_VHR + b*224 + j] = ar;
    ws[WS_VHI + b*224 + j] = ai;
}

// ---------------- kernel C2: boundary scan S_{b+1} = lambda^LB S_b + V^_b ----------
// stores S_{b+1} in-place over V^_b slot b. Prefetch ring depth 8.
__global__ __launch_bounds__(256) void k_scan(float* __restrict__ ws)
{
    const int j = threadIdx.x;
    if (j >= 221) return;
    const float decay = ws[WS_SC+0];
    float s, c;
    sincosf(TWO_PI_F * (float)j / 441.0f, &s, &c);
    float lr = 0.5f*decay*(1.0f + c);      // lambda_j = d/2 (1 + e^{-2 pi i j/441})
    float li = -0.5f*decay*s;
    float pr = 1.0f, pi = 0.0f, br = lr, bi = li;   // p = lambda^LB (binary power)
    int e = LB;
    while (e) {
        if (e & 1) { float t = pr*br - pi*bi; pi = pr*bi + pi*br; pr = t; }
        float t2 = br*br - bi*bi; bi = 2.0f*br*bi; br = t2;
        e >>= 1;
    }
    const int NV = NB - 1;                 // 249
    float sr = 0.0f, si = 0.0f;
    float cr8[8], ci8[8];
    #pragma unroll
    for (int d = 0; d < 8; ++d) {
        int idx = (d < NV) ? d : NV-1;
        cr8[d] = ws[WS_VHR + idx*224 + j];
        ci8[d] = ws[WS_VHI + idx*224 + j];
    }
    for (int base = 0; base < NV; base += 8) {
        float nr8[8], ni8[8];
        #pragma unroll
        for (int d = 0; d < 8; ++d) {
            int idx = base + 8 + d; if (idx >= NV) idx = NV-1;
            nr8[d] = ws[WS_VHR + idx*224 + j];
            ni8[d] = ws[WS_VHI + idx*224 + j];
        }
        #pragma unroll
        for (int d = 0; d < 8; ++d) {
            int bb = base + d;
            if (bb < NV) {
                float nr = pr*sr - pi*si + cr8[d];
                si = pr*si + pi*sr + ci8[d];
                sr = nr;
                ws[WS_VHR + bb*224 + j] = sr;    // = Re S_{bb+1}
                ws[WS_VHI + bb*224 + j] = si;
            }
        }
        #pragma unroll
        for (int d = 0; d < 8; ++d) { cr8[d] = nr8[d]; ci8[d] = ni8[d]; }
    }
}

// ---------------- kernel C3: IDFT of S_b -> time-domain block-entry state ----------
// real-signal form: corr[m] = (S_0 + 2*sum_{j=1}^{220} (Sr cos - Si sin)) / 441
__global__ __launch_bounds__(448) void k_idft(float* __restrict__ ws)
{
    __shared__ float SrS[221], SiS[221];
    const int b = blockIdx.x + 1;          // 1..NB-1
    const int tid = threadIdx.x;
    if (tid < 221) {
        SrS[tid] = ws[WS_VHR + (b-1)*224 + tid];
        SiS[tid] = ws[WS_VHI + (b-1)*224 + tid];
    }
    __syncthreads();
    if (tid >= 441) return;
    const int m = tid;
    const float cb = TWO_PI_F / 441.0f;
    float ss, sc;
    sincosf(cb * (float)m, &ss, &sc);      // step e^{+2 pi i m/441}
    float wr = sc, wi = ss;                // w at j=1
    float acc = SrS[0];
    int pm = m;                            // (j*m) mod 441, at loop head of iter j
    for (int jj = 1; jj <= 220; ++jj) {
        if ((jj & 31) == 0) sincosf(cb * (float)pm, &wi, &wr);  // resync
        float t = SrS[jj]*wr - SiS[jj]*wi;
        acc = fmaf(2.0f, t, acc);
        pm += m; if (pm >= 441) pm -= 441;
        float nr = wr*sc - wi*ss;
        float ni = wr*ss + wi*sc;
        wr = nr; wi = ni;
    }
    ws[WS_V + (b-1)*448 + m] = acc * (1.0f/441.0f);   // SB[b], aliases dead v storage
}

// ---------------- kernel D: true recurrence from reconstructed entry state --------
// fused envelope/fade/gain; single output write; no LDS, no barriers.
__global__ __launch_bounds__(64) void k_final(
    const float* __restrict__ fb, const float* __restrict__ t_in,
    const float* __restrict__ envp, const float* __restrict__ fade,
    float* __restrict__ out, const float* __restrict__ ws)
{
    const int b = blockIdx.x;              // 0..NB-1
    const int j = threadIdx.x;
    const bool act = j < 63;
    const float decay = ws[WS_SC+0];
    const float famt  = ws[WS_SC+1];
    const float gain  = ws[WS_SC+2];
    const float d2 = 0.5f * decay;
    const float a_  = fabsf(envp[0]) + 1e-3f;
    const float sus = envp[1];
    const float rr  = fabsf(envp[2]) + 1e-3f;
    const float inv_a = 1.0f / a_;
    const float inv_r = 1.0f / rr;
    const float sg = sus * gain;
    const float T = t_in[N_SAMP - 1];
    const int src = (j == 0) ? 62 : j - 1;
    const int i0 = b * LB;
    float cur[7];
    #pragma unroll
    for (int k = 0; k < 7; ++k) {
        int p = 63*k + j;
        cur[k] = act ? ((b == 0) ? ws[WS_WT + p] : ws[WS_V + (b-1)*448 + p]) : 0.0f;
    }
    float r[PF][7];
    #pragma unroll
    for (int p = 0; p < PF; ++p) {
        #pragma unroll
        for (int k = 0; k < 7; ++k)
            r[p][k] = act ? fb[(i0 + p)*WSZ + 63*k + j] : 0.0f;
    }
    for (int io = 0; io < LB/PF; ++io) {
        #pragma unroll
        for (int p = 0; p < PF; ++p) {
            const int i = i0 + io*PF + p;
            float x[7];
            #pragma unroll
            for (int k = 0; k < 7; ++k) x[k] = fmaf(famt, r[p][k], cur[k]);
            int inext = i + PF; if (inext > i0 + LB - 1) inext = i0 + LB - 1;
            #pragma unroll
            for (int k = 0; k < 7; ++k)
                r[p][k] = act ? fb[inext*WSZ + 63*k + j] : 0.0f;
            float sh[7];
            #pragma unroll
            for (int k = 0; k < 7; ++k) sh[k] = __shfl(x[k], src);
            #pragma unroll
            for (int k = 0; k < 7; ++k) {
                float prev = (j == 0) ? sh[(k+6)%7] : sh[k];
                cur[k] = d2 * (x[k] + prev);
            }
            #pragma unroll
            for (int k = 0; k < 7; ++k) {
                const int idx = i*WSZ + 63*k + j;
                float tt = (float)idx * INV_SR;               // exact: idx < 2^23
                float ca  = fminf(tt * inv_a, 1.0f);
                float crr = fminf(fmaxf((T - tt) * inv_r, 0.0f), 1.0f);
                float val = cur[k] * (ca * crr * sg);
                if (idx >= FADE_START) val *= fade[idx - FADE_START];
                if (act) out[idx] = val;
            }
        }
    }
}

// ---------------- fallback: fully sequential single block (no workspace) ----------
__global__ __launch_bounds__(448) void k_naive(
    const float* __restrict__ fb, const float* __restrict__ h,
    const float* __restrict__ t_in, const float* __restrict__ noise,
    const float* __restrict__ W1, const float* __restrict__ b1v,
    const float* __restrict__ W2, const float* __restrict__ b2v,
    const float* __restrict__ lpcut, const float* __restrict__ envp,
    const float* __restrict__ fade, float* __restrict__ out)
{
    __shared__ float hid[128];
    __shared__ float lat[5];
    __shared__ float wt[WSZ];
    __shared__ float buf[2][448];
    const int j = threadIdx.x;
    if (j < 128) {
        float acc = b1v[j];
        #pragma unroll
        for (int i = 0; i < 9; ++i) acc = acc + h[i] * W1[i*128 + j];
        hid[j] = fmaxf(acc, 0.0f);
    }
    __syncthreads();
    if (j < 5) {
        float a = b2v[j];
        for (int k = 0; k < 128; ++k) a = a + hid[k] * W2[k*5 + j];
        lat[j] = fmaxf(a, 0.0f);
    }
    __syncthreads();
    if (j == 0) {
        float lpf = fminf(fmaxf(lat[1]*44100.0f/4.0f, 100.0f), 22049.0f);
        float lpq = fminf(fmaxf(lat[2], 0.1f), 0.999f);
        run_biquads(noise, lpf, lpq, lpcut[0], wt);
    }
    __syncthreads();
    const float decay = fminf(fmaxf(lat[0]/10.0f + 0.9f, 0.9f), 0.999f);
    const float famt = lat[3];
    const float gain = lat[4];
    const float d2 = 0.5f * decay;
    const float a_  = fabsf(envp[0]) + 1e-3f;
    const float sus = envp[1];
    const float rr  = fabsf(envp[2]) + 1e-3f;
    const float inv_a = 1.0f / a_, inv_r = 1.0f / rr;
    const float T = t_in[N_SAMP - 1];
    const bool act = j < WSZ;
    const int jm1 = (j == 0) ? (WSZ - 1) : (j - 1);
    float cur = act ? wt[j] : 0.0f;
    for (int i = 0; i < NC; ++i) {
        float x = cur + famt * (act ? fb[i*WSZ + j] : 0.0f);
        buf[i&1][j] = x;
        __syncthreads();
        cur = d2 * (x + buf[i&1][jm1]);
        const int idx = i*WSZ + j;
        float val = cur;
        if (idx >= FADE_START) val *= fade[idx - FADE_START];
        float tt = act ? t_in[idx] : 0.0f;
        float ca  = fminf(fmaxf(tt * inv_a, 0.0f), 1.0f);
        float cr2 = fminf(fmaxf((T - tt) * inv_r, 0.0f), 1.0f);
        val = val * (ca * cr2 * sus) * gain;
        if (act) out[idx] = val;
    }
}

extern "C" void kernel_launch(void* const* d_in, const int* in_sizes, int n_in,
                              void* d_out, int out_size, void* d_ws, size_t ws_size,
                              hipStream_t stream) {
    const float* fb   = (const float*)d_in[0];
    const float* h    = (const float*)d_in[1];
    const float* t    = (const float*)d_in[2];
    const float* nz   = (const float*)d_in[3];
    const float* W1   = (const float*)d_in[4];
    const float* b1v  = (const float*)d_in[5];
    const float* W2   = (const float*)d_in[6];
    const float* b2v  = (const float*)d_in[7];
    const float* lpc  = (const float*)d_in[8];
    const float* envp = (const float*)d_in[9];
    const float* fade = (const float*)d_in[10];
    float* out = (float*)d_out;
    float* ws  = (float*)d_ws;

    if (ws_size < WS_NEED) {
        k_naive<<<1, 448, 0, stream>>>(fb, h, t, nz, W1, b1v, W2, b2v, lpc, envp, fade, out);
        return;
    }
    k_setup<<<1,    128, 0, stream>>>(h, nz, W1, b1v, W2, b2v, lpc, ws);
    k_state<<<NB-1,  64, 0, stream>>>(fb, ws);
    k_dft  <<<NB-1, 256, 0, stream>>>(ws);
    k_scan <<<1,    256, 0, stream>>>(ws);
    k_idft <<<NB-1, 448, 0, stream>>>(ws);
    k_final<<<NB,    64, 0, stream>>>(fb, t, envp, fade, out, ws);
}

// Round 4
// 115.406 us; speedup vs baseline: 1.6779x; 1.3382x over previous
//
#include <hip/hip_runtime.h>

#define N_SAMP   4410000
#define WSZ      441
#define NC       10000
#define NB       250
#define LB       40           // NB*LB == NC
#define PF       10           // fb prefetch ring depth
#define TWO_PI_F 6.28318530717958647692f
#define FADE_START (N_SAMP - 256)
#define INV_SR   (1.0f/44100.0f)

// workspace layout (floats). Slot lifecycle: v_b -> Vhat_b -> S_{b+1} -> SB[b+1]
#define WS_WT   0                          // 441 wavetable (padded 448)
#define WS_SC   448                        // [0]=decay [1]=feedbackamt [2]=gain
#define WS_SLOT(b) (512 + (b)*448)         // b = 0..NB-2
#define WS_NEED ((size_t)(512 + (NB-1)*448) * sizeof(float))

static_assert(NB * LB == NC, "block decomposition");

__device__ __forceinline__ void bq_coefs(float f, float q,
    float& b0, float& b1, float& b2, float& a1, float& a2)
{
    float w0 = TWO_PI_F * f / 44100.0f;
    float cw = cosf(w0), sw = sinf(w0);
    float al = sw / (2.0f * q);
    float a0 = 1.0f + al;
    b0 = ((1.0f - cw) * 0.5f) / a0;
    b1 = (1.0f - cw) / a0;
    b2 = ((1.0f - cw) * 0.5f) / a0;
    a1 = (-2.0f * cw) / a0;
    a2 = (1.0f - al) / a0;
}

// serial biquad pair (fallback kernel only)
__device__ __forceinline__ void run_biquads(const float* __restrict__ noise,
    float lpf, float lpq, float f2, float* dst)
{
    float c10,c11,c12,c13,c14, c20,c21,c22,c23,c24;
    bq_coefs(lpf, lpq, c10,c11,c12,c13,c14);
    bq_coefs(f2, 0.707f, c20,c21,c22,c23,c24);
    float s11=0.f,s12=0.f,s21=0.f,s22=0.f;
    for (int m = 0; m < WSZ; ++m) {
        float x  = noise[m];
        float y1 = c10*x + s11;
        s11 = c11*x - c13*y1 + s12;
        s12 = c12*x - c14*y1;
        float y2 = c20*y1 + s21;
        s21 = c21*y1 - c23*y2 + s22;
        s22 = c22*y1 - c24*y2;
        dst[m] = y2;
    }
}

// redundant per-block MLP: lane j computes hid cols j, j+64; shfl_xor reduce -> lat[5] on all lanes
__device__ __forceinline__ void mlp_latents(
    const float* __restrict__ h, const float* __restrict__ W1,
    const float* __restrict__ b1v, const float* __restrict__ W2,
    const float* __restrict__ b2v, int j, float lat[5])
{
    float hc0 = b1v[j], hc1 = b1v[j + 64];
    #pragma unroll
    for (int i = 0; i < 9; ++i) {
        float hv = h[i];
        hc0 = fmaf(hv, W1[i*128 + j], hc0);
        hc1 = fmaf(hv, W1[i*128 + j + 64], hc1);
    }
    hc0 = fmaxf(hc0, 0.f); hc1 = fmaxf(hc1, 0.f);
    float part[5];
    #pragma unroll
    for (int m = 0; m < 5; ++m)
        part[m] = fmaf(hc0, W2[j*5 + m], hc1 * W2[(j+64)*5 + m]);
    #pragma unroll
    for (int off = 32; off > 0; off >>= 1) {
        #pragma unroll
        for (int m = 0; m < 5; ++m)
            part[m] += __shfl_xor(part[m], off);
    }
    #pragma unroll
    for (int m = 0; m < 5; ++m)
        lat[m] = fmaxf(part[m] + b2v[m], 0.f);
}

// wave-parallel biquad over 441 samples: lane l holds positions 7l..7l+6.
// state map per sample: s' = Mg s + cg(x), Mg=[[-a1,1],[-a2,0]], cg=[(b1-a1 b0)x,(b2-a2 b0)x]
// local compose (7 samples) then Kogge-Stone compose scan over lanes; exclusive c = entry state.
__device__ __forceinline__ void biquad_wave(const float xin[7], float yout[7],
    float f, float q, int l)
{
    float b0,b1,b2,a1,a2;
    bq_coefs(f, q, b0,b1,b2,a1,a2);
    const float t1c = b1 - a1*b0;
    const float t2c = b2 - a2*b0;
    float m00=1.f,m01=0.f,m10=0.f,m11=1.f;
    float cv0=0.f, cv1=0.f;
    #pragma unroll
    for (int k = 0; k < 7; ++k) {
        float x = xin[k];
        float n0 = -a1*cv0 + cv1 + t1c*x;
        float n1 = -a2*cv0 + t2c*x;
        cv0 = n0; cv1 = n1;
        float r00 = -a1*m00 + m10, r01 = -a1*m01 + m11;
        float r10 = -a2*m00,       r11 = -a2*m01;
        m00=r00; m01=r01; m10=r10; m11=r11;
    }
    #pragma unroll
    for (int d = 1; d < 64; d <<= 1) {
        int srcl = l - d; int s2 = srcl < 0 ? 0 : srcl;
        float pm00=__shfl(m00,s2), pm01=__shfl(m01,s2);
        float pm10=__shfl(m10,s2), pm11=__shfl(m11,s2);
        float pc0=__shfl(cv0,s2), pc1=__shfl(cv1,s2);
        if (srcl >= 0) {
            float nc0 = m00*pc0 + m01*pc1 + cv0;
            float nc1 = m10*pc0 + m11*pc1 + cv1;
            float n00 = m00*pm00 + m01*pm10;
            float n01 = m00*pm01 + m01*pm11;
            float n10 = m10*pm00 + m11*pm10;
            float n11 = m10*pm01 + m11*pm11;
            m00=n00; m01=n01; m10=n10; m11=n11; cv0=nc0; cv1=nc1;
        }
    }
    int esrc = (l == 0) ? 0 : l - 1;
    float e0 = __shfl(cv0, esrc);
    float e1 = __shfl(cv1, esrc);
    float s1  = (l == 0) ? 0.f : e0;
    float s2v = (l == 0) ? 0.f : e1;
    #pragma unroll
    for (int k = 0; k < 7; ++k) {
        float x = xin[k];
        float y = b0*x + s1;
        float ns1 = b1*x - a1*y + s2v;
        s2v = b2*x - a2*y;
        s1 = ns1;
        yout[k] = y;
    }
}

// ---------------- kernel 1: fused setup + per-block local scan ----------------
// lane j holds positions p = 63k + j (k=0..6), j<63 active. Fully unrolled, ring in regs.
__global__ __launch_bounds__(64, 2) void k_state(
    const float* __restrict__ fb, const float* __restrict__ h,
    const float* __restrict__ noise, const float* __restrict__ W1,
    const float* __restrict__ b1v, const float* __restrict__ W2,
    const float* __restrict__ b2v, const float* __restrict__ lpcut,
    float* __restrict__ ws)
{
    __shared__ float wt_lds[441];
    const int b = blockIdx.x;              // 0..NB-2
    const int j = threadIdx.x;
    const bool act = j < 63;
    const int i0 = b * LB;

    // issue fb prefetch ring first (hides under MLP/biquad)
    float r[PF][7];
    #pragma unroll
    for (int p = 0; p < PF; ++p)
        #pragma unroll
        for (int k = 0; k < 7; ++k)
            r[p][k] = act ? fb[(i0 + p)*WSZ + 63*k + j] : 0.f;

    float lat[5];
    mlp_latents(h, W1, b1v, W2, b2v, j, lat);
    const float decay = fminf(fmaxf(lat[0]/10.0f + 0.9f, 0.9f), 0.999f);
    const float famt  = lat[3];
    const float d2 = 0.5f * decay;
    const int src = (j == 0) ? 62 : j - 1;

    float cur[7];
    if (b == 0) {
        if (j == 0) {
            ws[WS_SC+0] = decay;
            ws[WS_SC+1] = famt;
            ws[WS_SC+2] = lat[4];
        }
        const float lpf = fminf(fmaxf(lat[1]*44100.0f/4.0f, 100.0f), 22049.0f);
        const float lpq = fminf(fmaxf(lat[2], 0.1f), 0.999f);
        const float f2  = lpcut[0];
        float xin[7], y1[7], y2[7];
        #pragma unroll
        for (int k = 0; k < 7; ++k) xin[k] = act ? noise[7*j + k] : 0.f;
        biquad_wave(xin, y1, lpf, lpq, j);
        biquad_wave(y1, y2, f2, 0.707f, j);
        if (act) {
            #pragma unroll
            for (int k = 0; k < 7; ++k) {
                wt_lds[7*j + k] = y2[k];
                ws[WS_WT + 7*j + k] = y2[k];
            }
        }
        __syncthreads();
        #pragma unroll
        for (int k = 0; k < 7; ++k) cur[k] = act ? wt_lds[63*k + j] : 0.f;
    } else {
        #pragma unroll
        for (int k = 0; k < 7; ++k) cur[k] = 0.f;
    }

    #pragma unroll
    for (int i = 0; i < LB; ++i) {
        float x[7];
        #pragma unroll
        for (int k = 0; k < 7; ++k) x[k] = fmaf(famt, r[i%PF][k], cur[k]);
        if (i + PF < LB) {                 // compile-time after unroll
            #pragma unroll
            for (int k = 0; k < 7; ++k)
                r[i%PF][k] = act ? fb[(i0 + i + PF)*WSZ + 63*k + j] : 0.f;
        }
        float sh[7];
        #pragma unroll
        for (int k = 0; k < 7; ++k) sh[k] = __shfl(x[k], src);
        #pragma unroll
        for (int k = 0; k < 7; ++k)
            cur[k] = d2 * (x[k] + ((j == 0) ? sh[(k+6)%7] : sh[k]));
    }
    if (act) {
        #pragma unroll
        for (int k = 0; k < 7; ++k)
            ws[WS_SLOT(b) + 63*k + j] = cur[k];
    }
}

// ---------------- kernel 2: forward DFT of v_b, modes 0..220 (conj symmetry) ------
__global__ __launch_bounds__(256) void k_dft(float* __restrict__ ws)
{
    __shared__ float vs_[441];
    const int b = blockIdx.x;              // 0..NB-2
    const int tid = threadIdx.x;
    for (int m = tid; m < 441; m += 256) vs_[m] = ws[WS_SLOT(b) + m];
    __syncthreads();
    const int j = tid;
    if (j >= 221) return;
    const float cb = -TWO_PI_F / 441.0f;
    float ss, sc;
    sincosf(cb * (float)j, &ss, &sc);      // step e^{-2 pi i j/441}
    float wr = 1.0f, wi = 0.0f, ar = 0.0f, ai = 0.0f;
    int pm = 0;                            // (j*m) mod 441
    for (int m = 0; m < 441; ++m) {
        if ((m & 31) == 0) sincosf(cb * (float)pm, &wi, &wr);   // resync
        float v = vs_[m];
        ar = fmaf(v, wr, ar);
        ai = fmaf(v, wi, ai);
        pm += j; if (pm >= 441) pm -= 441;
        float nr = wr*sc - wi*ss;
        float ni = wr*ss + wi*sc;
        wr = nr; wi = ni;
    }
    ws[WS_SLOT(b) + j]       = ar;         // overwrite v (fully staged in LDS)
    ws[WS_SLOT(b) + 224 + j] = ai;
}

// ---------------- kernel 3: boundary scan S_{b+1} = lambda^LB S_b + Vhat_b --------
__global__ __launch_bounds__(256) void k_scan(float* __restrict__ ws)
{
    const int j = threadIdx.x;
    if (j >= 221) return;
    const float decay = ws[WS_SC+0];
    float s, c;
    sincosf(TWO_PI_F * (float)j / 441.0f, &s, &c);
    float lr = 0.5f*decay*(1.0f + c);      // lambda_j = d/2 (1 + e^{-2 pi i j/441})
    float li = -0.5f*decay*s;
    float pr = 1.0f, pi = 0.0f, br = lr, bi = li;   // p = lambda^LB
    int e = LB;
    while (e) {
        if (e & 1) { float t = pr*br - pi*bi; pi = pr*bi + pi*br; pr = t; }
        float t2 = br*br - bi*bi; bi = 2.0f*br*bi; br = t2;
        e >>= 1;
    }
    const int NV = NB - 1;                 // 249
    float sr = 0.0f, si = 0.0f;
    float cr8[8], ci8[8];
    #pragma unroll
    for (int d = 0; d < 8; ++d) {
        int idx = (d < NV) ? d : NV-1;
        cr8[d] = ws[WS_SLOT(idx) + j];
        ci8[d] = ws[WS_SLOT(idx) + 224 + j];
    }
    for (int base = 0; base < NV; base += 8) {
        float nr8[8], ni8[8];
        #pragma unroll
        for (int d = 0; d < 8; ++d) {
            int idx = base + 8 + d; if (idx >= NV) idx = NV-1;
            nr8[d] = ws[WS_SLOT(idx) + j];
            ni8[d] = ws[WS_SLOT(idx) + 224 + j];
        }
        #pragma unroll
        for (int d = 0; d < 8; ++d) {
            int bb = base + d;
            if (bb < NV) {
                float t1 = pr*sr - pi*si + cr8[d];
                si = pr*si + pi*sr + ci8[d];
                sr = t1;
                ws[WS_SLOT(bb) + j]       = sr;   // = Re S_{bb+1}
                ws[WS_SLOT(bb) + 224 + j] = si;
            }
        }
        #pragma unroll
        for (int d = 0; d < 8; ++d) { cr8[d] = nr8[d]; ci8[d] = ni8[d]; }
    }
}

// ---------------- kernel 4: IDFT of S_b -> block-entry correction state -----------
__global__ __launch_bounds__(448) void k_idft(float* __restrict__ ws)
{
    __shared__ float SrS[221], SiS[221];
    const int b = blockIdx.x + 1;          // 1..NB-1
    const int tid = threadIdx.x;
    if (tid < 221) {
        SrS[tid] = ws[WS_SLOT(b-1) + tid];
        SiS[tid] = ws[WS_SLOT(b-1) + 224 + tid];
    }
    __syncthreads();
    if (tid >= 441) return;
    const int m = tid;
    const float cb = TWO_PI_F / 441.0f;
    float ss, sc;
    sincosf(cb * (float)m, &ss, &sc);      // step e^{+2 pi i m/441}
    float wr = sc, wi = ss;                // w at j=1
    float acc = SrS[0];
    int pm = m;
    for (int jj = 1; jj <= 220; ++jj) {
        if ((jj & 31) == 0) sincosf(cb * (float)pm, &wi, &wr);  // resync
        float t = SrS[jj]*wr - SiS[jj]*wi;
        acc = fmaf(2.0f, t, acc);
        pm += m; if (pm >= 441) pm -= 441;
        float nr = wr*sc - wi*ss;
        float ni = wr*ss + wi*sc;
        wr = nr; wi = ni;
    }
    ws[WS_SLOT(b-1) + m] = acc * (1.0f/441.0f);   // SB[b]
}

// ---------------- kernel 5: true recurrence from entry state + env/fade/gain ------
__global__ __launch_bounds__(64, 2) void k_final(
    const float* __restrict__ fb, const float* __restrict__ t_in,
    const float* __restrict__ envp, const float* __restrict__ fade,
    float* __restrict__ out, const float* __restrict__ ws)
{
    const int b = blockIdx.x;              // 0..NB-1
    const int j = threadIdx.x;
    const bool act = j < 63;
    const int i0 = b * LB;

    float r[PF][7];
    #pragma unroll
    for (int p = 0; p < PF; ++p)
        #pragma unroll
        for (int k = 0; k < 7; ++k)
            r[p][k] = act ? fb[(i0 + p)*WSZ + 63*k + j] : 0.f;

    const float decay = ws[WS_SC+0];
    const float famt  = ws[WS_SC+1];
    const float gain  = ws[WS_SC+2];
    const float d2 = 0.5f * decay;
    const float a_  = fabsf(envp[0]) + 1e-3f;
    const float sus = envp[1];
    const float rr  = fabsf(envp[2]) + 1e-3f;
    const float inv_a = 1.0f / a_;
    const float inv_r = 1.0f / rr;
    const float sg = sus * gain;
    const float T = t_in[N_SAMP - 1];
    const int src = (j == 0) ? 62 : j - 1;

    // block-uniform fast path: entire block has ca=1, crr=1, no fade
    const float t_lo = (float)(i0*WSZ) * INV_SR;
    const float t_hi = (float)((i0+LB)*WSZ - 1) * INV_SR;
    const bool fastenv = (t_lo * inv_a >= 1.0f) &&
                         ((T - t_hi) * inv_r >= 1.0f) &&
                         ((i0+LB)*WSZ <= FADE_START);

    float cur[7];
    #pragma unroll
    for (int k = 0; k < 7; ++k) {
        int p = 63*k + j;
        cur[k] = act ? ((b == 0) ? ws[WS_WT + p] : ws[WS_SLOT(b-1) + p]) : 0.f;
    }

    #pragma unroll
    for (int i = 0; i < LB; ++i) {
        const int ii = i0 + i;
        float x[7];
        #pragma unroll
        for (int k = 0; k < 7; ++k) x[k] = fmaf(famt, r[i%PF][k], cur[k]);
        if (i + PF < LB) {
            #pragma unroll
            for (int k = 0; k < 7; ++k)
                r[i%PF][k] = act ? fb[(ii + PF)*WSZ + 63*k + j] : 0.f;
        }
        float sh[7];
        #pragma unroll
        for (int k = 0; k < 7; ++k) sh[k] = __shfl(x[k], src);
        #pragma unroll
        for (int k = 0; k < 7; ++k)
            cur[k] = d2 * (x[k] + ((j == 0) ? sh[(k+6)%7] : sh[k]));
        if (fastenv) {
            #pragma unroll
            for (int k = 0; k < 7; ++k)
                if (act) out[ii*WSZ + 63*k + j] = cur[k] * sg;
        } else {
            #pragma unroll
            for (int k = 0; k < 7; ++k) {
                const int idx = ii*WSZ + 63*k + j;
                float tt = (float)idx * INV_SR;   // exact int->float: idx < 2^23
                float ca  = fminf(tt * inv_a, 1.0f);
                float crr = fminf(fmaxf((T - tt) * inv_r, 0.0f), 1.0f);
                float val = cur[k] * (ca * crr * sg);
                if (idx >= FADE_START) val *= fade[idx - FADE_START];
                if (act) out[idx] = val;
            }
        }
    }
}

// ---------------- fallback: fully sequential single block (no workspace) ----------
__global__ __launch_bounds__(448) void k_naive(
    const float* __restrict__ fb, const float* __restrict__ h,
    const float* __restrict__ t_in, const float* __restrict__ noise,
    const float* __restrict__ W1, const float* __restrict__ b1v,
    const float* __restrict__ W2, const float* __restrict__ b2v,
    const float* __restrict__ lpcut, const float* __restrict__ envp,
    const float* __restrict__ fade, float* __restrict__ out)
{
    __shared__ float hid[128];
    __shared__ float lat[5];
    __shared__ float wt[WSZ];
    __shared__ float buf[2][448];
    const int j = threadIdx.x;
    if (j < 128) {
        float acc = b1v[j];
        #pragma unroll
        for (int i = 0; i < 9; ++i) acc = acc + h[i] * W1[i*128 + j];
        hid[j] = fmaxf(acc, 0.0f);
    }
    __syncthreads();
    if (j < 5) {
        float a = b2v[j];
        for (int k = 0; k < 128; ++k) a = a + hid[k] * W2[k*5 + j];
        lat[j] = fmaxf(a, 0.0f);
    }
    __syncthreads();
    if (j == 0) {
        float lpf = fminf(fmaxf(lat[1]*44100.0f/4.0f, 100.0f), 22049.0f);
        float lpq = fminf(fmaxf(lat[2], 0.1f), 0.999f);
        run_biquads(noise, lpf, lpq, lpcut[0], wt);
    }
    __syncthreads();
    const float decay = fminf(fmaxf(lat[0]/10.0f + 0.9f, 0.9f), 0.999f);
    const float famt = lat[3];
    const float gain = lat[4];
    const float d2 = 0.5f * decay;
    const float a_  = fabsf(envp[0]) + 1e-3f;
    const float sus = envp[1];
    const float rr  = fabsf(envp[2]) + 1e-3f;
    const float inv_a = 1.0f / a_, inv_r = 1.0f / rr;
    const float T = t_in[N_SAMP - 1];
    const bool act = j < WSZ;
    const int jm1 = (j == 0) ? (WSZ - 1) : (j - 1);
    float cur = act ? wt[j] : 0.0f;
    for (int i = 0; i < NC; ++i) {
        float x = cur + famt * (act ? fb[i*WSZ + j] : 0.0f);
        buf[i&1][j] = x;
        __syncthreads();
        cur = d2 * (x + buf[i&1][jm1]);
        const int idx = i*WSZ + j;
        float val = cur;
        if (idx >= FADE_START) val *= fade[idx - FADE_START];
        float tt = act ? t_in[idx] : 0.0f;
        float ca  = fminf(fmaxf(tt * inv_a, 0.0f), 1.0f);
        float cr2 = fminf(fmaxf((T - tt) * inv_r, 0.0f), 1.0f);
        val = val * (ca * cr2 * sus) * gain;
        if (act) out[idx] = val;
    }
}

extern "C" void kernel_launch(void* const* d_in, const int* in_sizes, int n_in,
                              void* d_out, int out_size, void* d_ws, size_t ws_size,
                              hipStream_t stream) {
    const float* fb   = (const float*)d_in[0];
    const float* h    = (const float*)d_in[1];
    const float* t    = (const float*)d_in[2];
    const float* nz   = (const float*)d_in[3];
    const float* W1   = (const float*)d_in[4];
    const float* b1v  = (const float*)d_in[5];
    const float* W2   = (const float*)d_in[6];
    const float* b2v  = (const float*)d_in[7];
    const float* lpc  = (const float*)d_in[8];
    const float* envp = (const float*)d_in[9];
    const float* fade = (const float*)d_in[10];
    float* out = (float*)d_out;
    float* ws  = (float*)d_ws;

    if (ws_size < WS_NEED) {
        k_naive<<<1, 448, 0, stream>>>(fb, h, t, nz, W1, b1v, W2, b2v, lpc, envp, fade, out);
        return;
    }
    k_state<<<NB-1,  64, 0, stream>>>(fb, h, nz, W1, b1v, W2, b2v, lpc, ws);
    k_dft  <<<NB-1, 256, 0, stream>>>(ws);
    k_scan <<<1,    256, 0, stream>>>(ws);
    k_idft <<<NB-1, 448, 0, stream>>>(ws);
    k_final<<<NB,    64, 0, stream>>>(fb, t, envp, fade, out, ws);
}